// Round 6
// baseline (238.836 us; speedup 1.0000x reference)
//
#include <hip/hip_runtime.h>
#include <hip/hip_bf16.h>

#define Hh 512
#define Pp 256
#define Ll 4096
#define Bb 8
#define BL (Bb*Ll)      // 32768
#define Sc 64
#define NC 64

typedef __attribute__((ext_vector_type(8))) __bf16 bf16x8;
typedef __attribute__((ext_vector_type(4))) float  floatx4;

// ws offsets in float2 units (8 B each; all 16B-aligned)
#define LAM_OFF     0                        // f32 lambda_bar [256]
#define G_OFF       256                      // f32 g [256]
#define LAMS64D_OFF 512                      // double2 lambda^64 [256] (512 slots)
#define B1G_OFF     1024                     // bf16 [512 n][512 k]
#define B3G_OFF     (B1G_OFF + 65536)        // bf16 [512 n][512 k]
#define BUB_OFF     (B3G_OFF + 65536)        // bf16 Bu [32768][512]
#define XSB_OFF     (BUB_OFF + 4194304)      // bf16 xs [32768][512]
#define AGG_OFF     (XSB_OFF + 4194304)      // float2 [512*256]

#define OUT_ELEMS 16777216                   // then state planar [2048 re][2048 im]

#define GLL16(g, l) __builtin_amdgcn_global_load_lds( \
    (const __attribute__((address_space(1))) void*)(g), \
    (__attribute__((address_space(3))) void*)(l), 16, 0, 0)

__device__ __forceinline__ float2 cmul(float2 a, float2 b) {
    float r = a.x*b.x - a.y*b.y;
    float i = a.x*b.y + a.y*b.x;
    return make_float2(r, i);
}
// acc += a*b (complex fma)
__device__ __forceinline__ void cfma(float2& acc, float2 a, float2 b) {
    acc.x = fmaf(a.x, b.x, acc.x); acc.x = fmaf(-a.y, b.y, acc.x);
    acc.y = fmaf(a.x, b.y, acc.y); acc.y = fmaf( a.y, b.x, acc.y);
}

// ---- K0a: per-p scalars in double ----
__global__ void k0a(const float* __restrict__ Lre, const float* __restrict__ Lim,
                    const float* __restrict__ logstep, float2* __restrict__ ws) {
    int p = threadIdx.x;
    double lr = (double)Lre[p], li = (double)Lim[p];
    double st = exp((double)logstep[p]);
    double a  = lr * st, th = li * st;
    double er = exp(a);
    double lamr = er * cos(th), lami = er * sin(th);
    ws[LAM_OFF + p] = make_float2((float)lamr, (float)lami);
    double er64 = exp(64.0 * a), th64 = 64.0 * th;
    ((double2*)(ws + LAMS64D_OFF))[p] = make_double2(er64 * cos(th64), er64 * sin(th64));
    double nr = lamr - 1.0, ni = lami;
    double den = lr*lr + li*li;
    ws[G_OFF + p] = make_float2((float)((nr*lr + ni*li)/den), (float)((ni*lr - nr*li)/den));
}

// ---- K0bc: build both weight matrices (bf16) ----
__global__ void k0bc(const float* __restrict__ Bmat, const float* __restrict__ Cmat,
                     float2* __restrict__ ws) {
    int bid = blockIdx.x;
    if (bid < 512) {
        int idx = bid * 256 + threadIdx.x;      // = p*512+h
        int p = idx >> 9, h = idx & 511;
        float2 b = ((const float2*)Bmat)[idx];
        float2 g = ws[G_OFF + p];
        float re = g.x*b.x - g.y*b.y;
        float im = g.x*b.y + g.y*b.x;
        __hip_bfloat16* B1 = (__hip_bfloat16*)(ws + B1G_OFF);
        B1[(2*p)*512 + h]   = __float2bfloat16(re);
        B1[(2*p+1)*512 + h] = __float2bfloat16(im);
    } else {
        int idx = (bid - 512) * 256 + threadIdx.x;  // = h*256+p
        int h = idx >> 8, p = idx & 255;
        float2 c = ((const float2*)Cmat)[idx];
        __hip_bfloat162* B3 = (__hip_bfloat162*)(ws + B3G_OFF);
        B3[h*256 + p] = __float22bfloat162_rn(make_float2(2.f*c.x, -2.f*c.y));
    }
}

// ---- GEMM1: Bu_bf16[32768][512] = u_f32[32768][512] * B1G[512][512]^T ----
// 128x128 tile, BK=32, 256 thr. A staged via VGPR->cvt->ds_write; B via GLL16.
__global__ void gemm1(const float* __restrict__ uf,
                      const __hip_bfloat16* __restrict__ Bg,
                      __hip_bfloat16* __restrict__ Cout) {
    __shared__ __align__(16) char lds[16384];   // A bf16: [0,8K), B: [8K,16K)
    const int tid = threadIdx.x;
    const int idx = blockIdx.x;
    const int mt  = (idx >> 5) * 8 + (idx & 7);   // XCD swizzle: 4 nt-siblings same XCD
    const int nt  = (idx >> 3) & 3;
    const long r0 = (long)mt * 128;
    const int  n0 = nt * 128;

    // A: fp32 staging. thread covers 16 fp32 (64 B): row=tid>>1, khalf=(tid&1)*16
    const int rowA = tid >> 1;
    const int kaH  = (tid & 1) * 16;
    const float* Af = uf + (r0 + rowA) * 512 + kaH;
    char* ldsAw = lds + rowA * 64 + kaH * 2;

    // B: GLL16 staging
    const int rowL = tid >> 2;
    const int seg  = tid & 3;
    const __hip_bfloat16* Bsrc = Bg + (long)(n0 + rowL) * 512 + seg * 8;
    char* ldsB = lds + 8192 + tid * 16;

    const int lane = tid & 63;
    const int quad = lane >> 4;
    const int ml   = lane & 15;
    const int w    = tid >> 6;
    const int wm   = w & 1, wn = w >> 1;

    floatx4 acc[4][4];
    #pragma unroll
    for (int i = 0; i < 4; ++i)
        #pragma unroll
        for (int j = 0; j < 4; ++j) acc[i][j] = (floatx4)0.f;

    for (int kt = 0; kt < 16; ++kt) {
        __syncthreads();
        GLL16(Bsrc + kt*32,           ldsB);
        GLL16(Bsrc + kt*32 + 64*512,  ldsB + 4096);
        float4 a0 = *(const float4*)(Af + kt*32);
        float4 a1 = *(const float4*)(Af + kt*32 + 4);
        float4 a2 = *(const float4*)(Af + kt*32 + 8);
        float4 a3 = *(const float4*)(Af + kt*32 + 12);
        __align__(16) __hip_bfloat162 tmp[8];
        tmp[0] = __float22bfloat162_rn(make_float2(a0.x, a0.y));
        tmp[1] = __float22bfloat162_rn(make_float2(a0.z, a0.w));
        tmp[2] = __float22bfloat162_rn(make_float2(a1.x, a1.y));
        tmp[3] = __float22bfloat162_rn(make_float2(a1.z, a1.w));
        tmp[4] = __float22bfloat162_rn(make_float2(a2.x, a2.y));
        tmp[5] = __float22bfloat162_rn(make_float2(a2.z, a2.w));
        tmp[6] = __float22bfloat162_rn(make_float2(a3.x, a3.y));
        tmp[7] = __float22bfloat162_rn(make_float2(a3.z, a3.w));
        *(bf16x8*)(ldsAw)      = *(const bf16x8*)&tmp[0];
        *(bf16x8*)(ldsAw + 16) = *(const bf16x8*)&tmp[4];
        __syncthreads();

        bf16x8 af[4], bf[4];
        #pragma unroll
        for (int fm = 0; fm < 4; ++fm)
            af[fm] = *(const bf16x8*)(lds + (wm*64 + fm*16 + ml)*64 + quad*16);
        #pragma unroll
        for (int fn = 0; fn < 4; ++fn)
            bf[fn] = *(const bf16x8*)(lds + 8192 + (wn*64 + fn*16 + ml)*64 + quad*16);
        #pragma unroll
        for (int fm = 0; fm < 4; ++fm)
            #pragma unroll
            for (int fn = 0; fn < 4; ++fn)
                acc[fm][fn] = __builtin_amdgcn_mfma_f32_16x16x32_bf16(af[fm], bf[fn], acc[fm][fn], 0, 0, 0);
    }

    #pragma unroll
    for (int fm = 0; fm < 4; ++fm)
        #pragma unroll
        for (int fn = 0; fn < 4; ++fn) {
            int col = n0 + wn*64 + fn*16 + ml;
            #pragma unroll
            for (int reg = 0; reg < 4; ++reg) {
                long row = r0 + wm*64 + fm*16 + quad*4 + reg;
                Cout[row * 512 + col] = __float2bfloat16(acc[fm][fn][reg]);
            }
        }
}

// ---- GEMM2: out_f32[32768][512] = xs_bf16 * B3G^T + Dv[col]*u_f32 ----
__global__ void gemm2(const __hip_bfloat16* __restrict__ Ab,
                      const __hip_bfloat16* __restrict__ Bg,
                      float* __restrict__ Cout,
                      const float* __restrict__ uf,
                      const float* __restrict__ Dv) {
    __shared__ __align__(16) char lds[16384];
    const int tid = threadIdx.x;
    const int idx = blockIdx.x;
    const int mt  = (idx >> 5) * 8 + (idx & 7);
    const int nt  = (idx >> 3) & 3;
    const long r0 = (long)mt * 128;
    const int  n0 = nt * 128;

    const int rowL = tid >> 2;
    const int seg  = tid & 3;
    const __hip_bfloat16* Asrc = Ab + (r0 + rowL) * 512 + seg * 8;
    const __hip_bfloat16* Bsrc = Bg + (long)(n0 + rowL) * 512 + seg * 8;
    char* ldsA = lds + tid * 16;
    char* ldsB = lds + 8192 + tid * 16;

    const int lane = tid & 63;
    const int quad = lane >> 4;
    const int ml   = lane & 15;
    const int w    = tid >> 6;
    const int wm   = w & 1, wn = w >> 1;

    floatx4 acc[4][4];
    #pragma unroll
    for (int i = 0; i < 4; ++i)
        #pragma unroll
        for (int j = 0; j < 4; ++j) acc[i][j] = (floatx4)0.f;

    for (int kt = 0; kt < 16; ++kt) {
        __syncthreads();
        GLL16(Asrc + kt*32,           ldsA);
        GLL16(Asrc + kt*32 + 64*512,  ldsA + 4096);
        GLL16(Bsrc + kt*32,           ldsB);
        GLL16(Bsrc + kt*32 + 64*512,  ldsB + 4096);
        __syncthreads();

        bf16x8 af[4], bf[4];
        #pragma unroll
        for (int fm = 0; fm < 4; ++fm)
            af[fm] = *(const bf16x8*)(lds + (wm*64 + fm*16 + ml)*64 + quad*16);
        #pragma unroll
        for (int fn = 0; fn < 4; ++fn)
            bf[fn] = *(const bf16x8*)(lds + 8192 + (wn*64 + fn*16 + ml)*64 + quad*16);
        #pragma unroll
        for (int fm = 0; fm < 4; ++fm)
            #pragma unroll
            for (int fn = 0; fn < 4; ++fn)
                acc[fm][fn] = __builtin_amdgcn_mfma_f32_16x16x32_bf16(af[fm], bf[fn], acc[fm][fn], 0, 0, 0);
    }

    #pragma unroll
    for (int fm = 0; fm < 4; ++fm)
        #pragma unroll
        for (int fn = 0; fn < 4; ++fn) {
            int col = n0 + wn*64 + fn*16 + ml;
            float d = Dv[col];
            #pragma unroll
            for (int reg = 0; reg < 4; ++reg) {
                long row = r0 + wm*64 + fm*16 + quad*4 + reg;
                long o = row * 512 + col;
                Cout[o] = acc[fm][fn][reg] + d * uf[o];
            }
        }
}

// ---- K2a: chunk aggregates with lambda-power grouping (8x shorter dep chain) ----
__global__ void k2a(float2* __restrict__ ws) {
    int p = threadIdx.x;
    int bc = blockIdx.x;              // b*NC + c
    int b = bc >> 6, c = bc & 63;
    float2 lam = ws[LAM_OFF + p];
    float2 lp[8];                     // lp[k] = lam^k
    lp[0] = make_float2(1.f, 0.f);
    #pragma unroll
    for (int k = 1; k < 8; ++k) lp[k] = cmul(lp[k-1], lam);
    float2 lam8 = cmul(lp[7], lam);
    const __hip_bfloat162* __restrict__ bub = (const __hip_bfloat162*)(ws + BUB_OFF);
    long base = (long)(b*Ll + c*Sc) * Pp + p;
    float2 agg = make_float2(0.f, 0.f);
    for (int j0 = 0; j0 < Sc; j0 += 8) {
        float2 v[8];
        #pragma unroll
        for (int i = 0; i < 8; ++i)
            v[i] = __bfloat1622float2(bub[base + (long)(j0 + i) * Pp]);
        // G = sum_i lam^(7-i) * v[i], two independent accumulators
        float2 s0 = make_float2(0.f, 0.f), s1 = make_float2(0.f, 0.f);
        #pragma unroll
        for (int i = 0; i < 8; i += 2) {
            cfma(s0, lp[7 - i], v[i]);
            cfma(s1, lp[6 - i], v[i + 1]);
        }
        float2 G = make_float2(s0.x + s1.x, s0.y + s1.y);
        float2 na = cmul(lam8, agg);
        agg = make_float2(na.x + G.x, na.y + G.y);
    }
    ws[AGG_OFF + bc * Pp + p] = agg;
}

// ---- K2c: fp64 carry prefix + apply + write xs bf16 + state planar ----
__global__ void k2c(float2* __restrict__ ws, float* __restrict__ dout) {
    int p = threadIdx.x;
    int bc = blockIdx.x;
    int b = bc >> 6, c = bc & 63;
    float2 lam = ws[LAM_OFF + p];
    double2 l64 = ((const double2*)(ws + LAMS64D_OFF))[p];
    double cr = 0.0, ci = 0.0;
    for (int cp = 0; cp < c; ++cp) {
        float2 a = ws[AGG_OFF + (b*NC + cp) * Pp + p];
        double nr = fma(l64.x, cr, (double)a.x); nr = fma(-l64.y, ci, nr);
        double ni = fma(l64.x, ci, (double)a.y); ni = fma( l64.y, cr, ni);
        cr = nr; ci = ni;
    }
    float2 x = make_float2((float)cr, (float)ci);
    const __hip_bfloat162* __restrict__ bub = (const __hip_bfloat162*)(ws + BUB_OFF);
    __hip_bfloat162* __restrict__ xsb = (__hip_bfloat162*)(ws + XSB_OFF);
    long base = (long)(b*Ll + c*Sc) * Pp + p;
    for (int j0 = 0; j0 < Sc; j0 += 8) {
        float2 v[8];
        #pragma unroll
        for (int i = 0; i < 8; ++i)
            v[i] = __bfloat1622float2(bub[base + (long)(j0 + i) * Pp]);
        #pragma unroll
        for (int i = 0; i < 8; ++i) {
            float nr = fmaf(lam.x, x.x, v[i].x); nr = fmaf(-lam.y, x.y, nr);
            float ni = fmaf(lam.x, x.y, v[i].y); ni = fmaf( lam.y, x.x, ni);
            x.x = nr; x.y = ni;
            xsb[base + (long)(j0 + i) * Pp] = __float22bfloat162_rn(make_float2(x.x, x.y));
        }
    }
    if (c == NC - 1) {
        dout[OUT_ELEMS + b * Pp + p] = x.x;
        dout[OUT_ELEMS + Bb * Pp + b * Pp + p] = x.y;
    }
}

extern "C" void kernel_launch(void* const* d_in, const int* in_sizes, int n_in,
                              void* d_out, int out_size, void* d_ws, size_t ws_size,
                              hipStream_t stream) {
    const float* u       = (const float*)d_in[0];
    const float* Lre     = (const float*)d_in[1];
    const float* Lim     = (const float*)d_in[2];
    const float* Bmat    = (const float*)d_in[3];
    const float* Cmat    = (const float*)d_in[4];
    const float* Dv      = (const float*)d_in[5];
    const float* logstep = (const float*)d_in[6];
    float*  out = (float*)d_out;
    float2* ws  = (float2*)d_ws;

    k0a<<<1, 256, 0, stream>>>(Lre, Lim, logstep, ws);
    k0bc<<<1024, 256, 0, stream>>>(Bmat, Cmat, ws);

    gemm1<<<1024, 256, 0, stream>>>(
        u, (const __hip_bfloat16*)(ws + B1G_OFF),
        (__hip_bfloat16*)(ws + BUB_OFF));

    k2a<<<Bb*NC, 256, 0, stream>>>(ws);
    k2c<<<Bb*NC, 256, 0, stream>>>(ws, out);

    gemm2<<<1024, 256, 0, stream>>>(
        (const __hip_bfloat16*)(ws + XSB_OFF),
        (const __hip_bfloat16*)(ws + B3G_OFF),
        out, u, Dv);
}

// Round 7
// 231.895 us; speedup vs baseline: 1.0299x; 1.0299x over previous
//
#include <hip/hip_runtime.h>
#include <hip/hip_bf16.h>

#define Hh 512
#define Pp 256
#define Ll 4096
#define Bb 8
#define BL (Bb*Ll)      // 32768
#define Sc 64
#define NC 64

typedef __attribute__((ext_vector_type(8))) __bf16 bf16x8;
typedef __attribute__((ext_vector_type(4))) float  floatx4;

// ws offsets in float2 units (8 B each; all 16B-aligned)
#define LAM_OFF     0                        // f32 lambda_bar [256]
#define LAMS64D_OFF 512                      // double2 lambda^64 [256] (512 slots)
#define B1G_OFF     1024                     // bf16 [512 n][512 k]
#define B3G_OFF     (B1G_OFF + 65536)        // bf16 [512 n][512 k]
#define BUB_OFF     (B3G_OFF + 65536)        // bf16 Bu [32768][512]
#define XSB_OFF     (BUB_OFF + 4194304)      // bf16 xs [32768][512]
#define AGG_OFF     (XSB_OFF + 4194304)      // float2 [512*256]

#define OUT_ELEMS 16777216                   // then state planar [2048 re][2048 im]

#define GLL16(g, l) __builtin_amdgcn_global_load_lds( \
    (const __attribute__((address_space(1))) void*)(g), \
    (__attribute__((address_space(3))) void*)(l), 16, 0, 0)

__device__ __forceinline__ float2 cmul(float2 a, float2 b) {
    return make_float2(a.x*b.x - a.y*b.y, a.x*b.y + a.y*b.x);
}
__device__ __forceinline__ void cfma(float2& acc, float2 a, float2 b) {
    acc.x = fmaf(a.x, b.x, acc.x); acc.x = fmaf(-a.y, b.y, acc.x);
    acc.y = fmaf(a.x, b.y, acc.y); acc.y = fmaf( a.y, b.x, acc.y);
}

// ---- PREP: grid 1025. bids 0..511: B1G. 512..1023: B3G. 1024: lambda scalars. ----
__global__ void prep(const float* __restrict__ Bmat, const float* __restrict__ Cmat,
                     const float* __restrict__ Lre, const float* __restrict__ Lim,
                     const float* __restrict__ logstep, float2* __restrict__ ws) {
    int bid = blockIdx.x;
    if (bid < 512) {
        int idx = bid * 256 + threadIdx.x;      // = p*512+h
        int p = idx >> 9, h = idx & 511;
        // g computed inline (fp64)
        double lr = (double)Lre[p], li = (double)Lim[p];
        double st = exp((double)logstep[p]);
        double a  = lr * st, th = li * st;
        double er = exp(a);
        double lamr = er * cos(th), lami = er * sin(th);
        double nr = lamr - 1.0, ni = lami;
        double den = lr*lr + li*li;
        float gx = (float)((nr*lr + ni*li)/den), gy = (float)((ni*lr - nr*li)/den);
        float2 b = ((const float2*)Bmat)[idx];
        float re = gx*b.x - gy*b.y;
        float im = gx*b.y + gy*b.x;
        __hip_bfloat16* B1 = (__hip_bfloat16*)(ws + B1G_OFF);
        B1[(2*p)*512 + h]   = __float2bfloat16(re);
        B1[(2*p+1)*512 + h] = __float2bfloat16(im);
    } else if (bid < 1024) {
        int idx = (bid - 512) * 256 + threadIdx.x;  // = h*256+p
        int h = idx >> 8, p = idx & 255;
        float2 c = ((const float2*)Cmat)[idx];
        __hip_bfloat162* B3 = (__hip_bfloat162*)(ws + B3G_OFF);
        B3[h*256 + p] = __float22bfloat162_rn(make_float2(2.f*c.x, -2.f*c.y));
    } else {
        int p = threadIdx.x;
        double lr = (double)Lre[p], li = (double)Lim[p];
        double st = exp((double)logstep[p]);
        double a  = lr * st, th = li * st;
        double er = exp(a);
        ws[LAM_OFF + p] = make_float2((float)(er*cos(th)), (float)(er*sin(th)));
        double er64 = exp(64.0 * a), th64 = 64.0 * th;
        ((double2*)(ws + LAMS64D_OFF))[p] = make_double2(er64*cos(th64), er64*sin(th64));
    }
}

// ---- GEMM1: Bu_bf16[32768][512] = u_f32 * B1G^T. 128x128, BK=32, 256 thr. ----
// A: fp32->bf16 cvt staged with conflict-free ds_write (chunk t & t+256 at t*16).
__global__ void gemm1(const float* __restrict__ uf,
                      const __hip_bfloat16* __restrict__ Bg,
                      __hip_bfloat16* __restrict__ Cout) {
    __shared__ __align__(16) char lds[16384];   // A bf16 [0,8K), B [8K,16K)
    const int tid = threadIdx.x;
    const int idx = blockIdx.x;
    const int mt  = (idx >> 5) * 8 + (idx & 7);   // XCD swizzle
    const int nt  = (idx >> 3) & 3;
    const long r0 = (long)mt * 128;
    const int  n0 = nt * 128;

    // A chunks: c -> row c>>2, k-seg (c&3)*8 floats; LDS byte c*16
    const int rowA1 = tid >> 2,          segA1 = tid & 3;
    const int rowA2 = (tid + 256) >> 2,  segA2 = tid & 3;
    const float* A1 = uf + (r0 + rowA1) * 512 + segA1 * 8;
    const float* A2 = uf + (r0 + rowA2) * 512 + segA2 * 8;
    char* ldsA1 = lds + tid * 16;
    char* ldsA2 = lds + 4096 + tid * 16;

    const int rowL = tid >> 2;
    const int seg  = tid & 3;
    const __hip_bfloat16* Bsrc = Bg + (long)(n0 + rowL) * 512 + seg * 8;
    char* ldsB = lds + 8192 + tid * 16;

    const int lane = tid & 63;
    const int quad = lane >> 4;
    const int ml   = lane & 15;
    const int w    = tid >> 6;
    const int wm   = w & 1, wn = w >> 1;

    floatx4 acc[4][4];
    #pragma unroll
    for (int i = 0; i < 4; ++i)
        #pragma unroll
        for (int j = 0; j < 4; ++j) acc[i][j] = (floatx4)0.f;

    for (int kt = 0; kt < 16; ++kt) {
        __syncthreads();
        GLL16(Bsrc + kt*32,           ldsB);
        GLL16(Bsrc + kt*32 + 64*512,  ldsB + 4096);
        float4 f0 = *(const float4*)(A1 + kt*32);
        float4 f1 = *(const float4*)(A1 + kt*32 + 4);
        float4 f2 = *(const float4*)(A2 + kt*32);
        float4 f3 = *(const float4*)(A2 + kt*32 + 4);
        __align__(16) __hip_bfloat162 t1[4], t2[4];
        t1[0] = __float22bfloat162_rn(make_float2(f0.x, f0.y));
        t1[1] = __float22bfloat162_rn(make_float2(f0.z, f0.w));
        t1[2] = __float22bfloat162_rn(make_float2(f1.x, f1.y));
        t1[3] = __float22bfloat162_rn(make_float2(f1.z, f1.w));
        t2[0] = __float22bfloat162_rn(make_float2(f2.x, f2.y));
        t2[1] = __float22bfloat162_rn(make_float2(f2.z, f2.w));
        t2[2] = __float22bfloat162_rn(make_float2(f3.x, f3.y));
        t2[3] = __float22bfloat162_rn(make_float2(f3.z, f3.w));
        *(bf16x8*)ldsA1 = *(const bf16x8*)t1;
        *(bf16x8*)ldsA2 = *(const bf16x8*)t2;
        __syncthreads();

        bf16x8 af[4], bfr[4];
        #pragma unroll
        for (int fm = 0; fm < 4; ++fm)
            af[fm] = *(const bf16x8*)(lds + (wm*64 + fm*16 + ml)*64 + quad*16);
        #pragma unroll
        for (int fn = 0; fn < 4; ++fn)
            bfr[fn] = *(const bf16x8*)(lds + 8192 + (wn*64 + fn*16 + ml)*64 + quad*16);
        #pragma unroll
        for (int fm = 0; fm < 4; ++fm)
            #pragma unroll
            for (int fn = 0; fn < 4; ++fn)
                acc[fm][fn] = __builtin_amdgcn_mfma_f32_16x16x32_bf16(af[fm], bfr[fn], acc[fm][fn], 0, 0, 0);
    }

    #pragma unroll
    for (int fm = 0; fm < 4; ++fm)
        #pragma unroll
        for (int fn = 0; fn < 4; ++fn) {
            int col = n0 + wn*64 + fn*16 + ml;
            #pragma unroll
            for (int reg = 0; reg < 4; ++reg) {
                long row = r0 + wm*64 + fm*16 + quad*4 + reg;
                Cout[row * 512 + col] = __float2bfloat16(acc[fm][fn][reg]);
            }
        }
}

// ---- GEMM2: out_f32 = xs_bf16 * B3G^T + Dv[col]*u_f32 ----
__global__ void gemm2(const __hip_bfloat16* __restrict__ Ab,
                      const __hip_bfloat16* __restrict__ Bg,
                      float* __restrict__ Cout,
                      const float* __restrict__ uf,
                      const float* __restrict__ Dv) {
    __shared__ __align__(16) char lds[16384];
    const int tid = threadIdx.x;
    const int idx = blockIdx.x;
    const int mt  = (idx >> 5) * 8 + (idx & 7);
    const int nt  = (idx >> 3) & 3;
    const long r0 = (long)mt * 128;
    const int  n0 = nt * 128;

    const int rowL = tid >> 2;
    const int seg  = tid & 3;
    const __hip_bfloat16* Asrc = Ab + (r0 + rowL) * 512 + seg * 8;
    const __hip_bfloat16* Bsrc = Bg + (long)(n0 + rowL) * 512 + seg * 8;
    char* ldsA = lds + tid * 16;
    char* ldsB = lds + 8192 + tid * 16;

    const int lane = tid & 63;
    const int quad = lane >> 4;
    const int ml   = lane & 15;
    const int w    = tid >> 6;
    const int wm   = w & 1, wn = w >> 1;

    floatx4 acc[4][4];
    #pragma unroll
    for (int i = 0; i < 4; ++i)
        #pragma unroll
        for (int j = 0; j < 4; ++j) acc[i][j] = (floatx4)0.f;

    for (int kt = 0; kt < 16; ++kt) {
        __syncthreads();
        GLL16(Asrc + kt*32,           ldsA);
        GLL16(Asrc + kt*32 + 64*512,  ldsA + 4096);
        GLL16(Bsrc + kt*32,           ldsB);
        GLL16(Bsrc + kt*32 + 64*512,  ldsB + 4096);
        __syncthreads();

        bf16x8 af[4], bfr[4];
        #pragma unroll
        for (int fm = 0; fm < 4; ++fm)
            af[fm] = *(const bf16x8*)(lds + (wm*64 + fm*16 + ml)*64 + quad*16);
        #pragma unroll
        for (int fn = 0; fn < 4; ++fn)
            bfr[fn] = *(const bf16x8*)(lds + 8192 + (wn*64 + fn*16 + ml)*64 + quad*16);
        #pragma unroll
        for (int fm = 0; fm < 4; ++fm)
            #pragma unroll
            for (int fn = 0; fn < 4; ++fn)
                acc[fm][fn] = __builtin_amdgcn_mfma_f32_16x16x32_bf16(af[fm], bfr[fn], acc[fm][fn], 0, 0, 0);
    }

    #pragma unroll
    for (int fm = 0; fm < 4; ++fm)
        #pragma unroll
        for (int fn = 0; fn < 4; ++fn) {
            int col = n0 + wn*64 + fn*16 + ml;
            float d = Dv[col];
            #pragma unroll
            for (int reg = 0; reg < 4; ++reg) {
                long row = r0 + wm*64 + fm*16 + quad*4 + reg;
                long o = row * 512 + col;
                Cout[o] = acc[fm][fn][reg] + d * uf[o];
            }
        }
}

// ---- K2a: chunk aggregates, lambda-power ILP grouping ----
__global__ void k2a(float2* __restrict__ ws) {
    int p = threadIdx.x;
    int bc = blockIdx.x;              // b*NC + c
    int b = bc >> 6, c = bc & 63;
    float2 lam = ws[LAM_OFF + p];
    float2 lp[8];
    lp[0] = make_float2(1.f, 0.f);
    #pragma unroll
    for (int k = 1; k < 8; ++k) lp[k] = cmul(lp[k-1], lam);
    float2 lam8 = cmul(lp[7], lam);
    const __hip_bfloat162* __restrict__ bub = (const __hip_bfloat162*)(ws + BUB_OFF);
    long base = (long)(b*Ll + c*Sc) * Pp + p;
    float2 agg = make_float2(0.f, 0.f);
    for (int j0 = 0; j0 < Sc; j0 += 8) {
        float2 v[8];
        #pragma unroll
        for (int i = 0; i < 8; ++i)
            v[i] = __bfloat1622float2(bub[base + (long)(j0 + i) * Pp]);
        float2 s0 = make_float2(0.f, 0.f), s1 = make_float2(0.f, 0.f);
        #pragma unroll
        for (int i = 0; i < 8; i += 2) {
            cfma(s0, lp[7 - i], v[i]);
            cfma(s1, lp[6 - i], v[i + 1]);
        }
        float2 G = make_float2(s0.x + s1.x, s0.y + s1.y);
        float2 na = cmul(lam8, agg);
        agg = make_float2(na.x + G.x, na.y + G.y);
    }
    ws[AGG_OFF + bc * Pp + p] = agg;
}

// ---- K2c: fp64 carry prefix + apply + write xs bf16 + state planar ----
__global__ void k2c(float2* __restrict__ ws, float* __restrict__ dout) {
    int p = threadIdx.x;
    int bc = blockIdx.x;
    int b = bc >> 6, c = bc & 63;
    float2 lam = ws[LAM_OFF + p];
    double2 l64 = ((const double2*)(ws + LAMS64D_OFF))[p];
    double cr = 0.0, ci = 0.0;
    for (int cp = 0; cp < c; ++cp) {
        float2 a = ws[AGG_OFF + (b*NC + cp) * Pp + p];
        double nr = fma(l64.x, cr, (double)a.x); nr = fma(-l64.y, ci, nr);
        double ni = fma(l64.x, ci, (double)a.y); ni = fma( l64.y, cr, ni);
        cr = nr; ci = ni;
    }
    float2 x = make_float2((float)cr, (float)ci);
    const __hip_bfloat162* __restrict__ bub = (const __hip_bfloat162*)(ws + BUB_OFF);
    __hip_bfloat162* __restrict__ xsb = (__hip_bfloat162*)(ws + XSB_OFF);
    long base = (long)(b*Ll + c*Sc) * Pp + p;
    for (int j0 = 0; j0 < Sc; j0 += 8) {
        float2 v[8];
        #pragma unroll
        for (int i = 0; i < 8; ++i)
            v[i] = __bfloat1622float2(bub[base + (long)(j0 + i) * Pp]);
        #pragma unroll
        for (int i = 0; i < 8; ++i) {
            float nr = fmaf(lam.x, x.x, v[i].x); nr = fmaf(-lam.y, x.y, nr);
            float ni = fmaf(lam.x, x.y, v[i].y); ni = fmaf( lam.y, x.x, ni);
            x.x = nr; x.y = ni;
            xsb[base + (long)(j0 + i) * Pp] = __float22bfloat162_rn(make_float2(x.x, x.y));
        }
    }
    if (c == NC - 1) {
        dout[OUT_ELEMS + b * Pp + p] = x.x;
        dout[OUT_ELEMS + Bb * Pp + b * Pp + p] = x.y;
    }
}

extern "C" void kernel_launch(void* const* d_in, const int* in_sizes, int n_in,
                              void* d_out, int out_size, void* d_ws, size_t ws_size,
                              hipStream_t stream) {
    const float* u       = (const float*)d_in[0];
    const float* Lre     = (const float*)d_in[1];
    const float* Lim     = (const float*)d_in[2];
    const float* Bmat    = (const float*)d_in[3];
    const float* Cmat    = (const float*)d_in[4];
    const float* Dv      = (const float*)d_in[5];
    const float* logstep = (const float*)d_in[6];
    float*  out = (float*)d_out;
    float2* ws  = (float2*)d_ws;

    prep<<<1025, 256, 0, stream>>>(Bmat, Cmat, Lre, Lim, logstep, ws);

    gemm1<<<1024, 256, 0, stream>>>(
        u, (const __hip_bfloat16*)(ws + B1G_OFF),
        (__hip_bfloat16*)(ws + BUB_OFF));

    k2a<<<Bb*NC, 256, 0, stream>>>(ws);
    k2c<<<Bb*NC, 256, 0, stream>>>(ws, out);

    gemm2<<<1024, 256, 0, stream>>>(
        (const __hip_bfloat16*)(ws + XSB_OFF),
        (const __hip_bfloat16*)(ws + B3G_OFF),
        out, u, Dv);
}

// Round 8
// 219.937 us; speedup vs baseline: 1.0859x; 1.0544x over previous
//
#include <hip/hip_runtime.h>
#include <hip/hip_bf16.h>

#define Hh 512
#define Pp 256
#define Ll 4096
#define Bb 8
#define BL (Bb*Ll)      // 32768
#define Sc 64
#define NC 64

typedef __attribute__((ext_vector_type(8))) __bf16 bf16x8;
typedef __attribute__((ext_vector_type(4))) float  floatx4;

// ws offsets in float2 units (8 B each; all 16B-aligned)
#define LAM_OFF     0                        // f32 lambda_bar [256]
#define LAMS64D_OFF 512                      // double2 lambda^64 [256] (512 slots)
#define B1G_OFF     1024                     // bf16 [512 n][512 k]
#define B3G_OFF     (B1G_OFF + 65536)        // bf16 [512 n][512 k]
#define UB16_OFF    (B3G_OFF + 65536)        // bf16 u [32768][512]
#define BUB_OFF     (UB16_OFF + 4194304)     // bf16 Bu [32768][512]
#define XSB_OFF     (BUB_OFF + 4194304)      // bf16 xs [32768][512]
#define AGG_OFF     (XSB_OFF + 4194304)      // float2 [512*256]

#define OUT_ELEMS 16777216                   // then state planar [2048 re][2048 im]

#define GLL16(g, l) __builtin_amdgcn_global_load_lds( \
    (const __attribute__((address_space(1))) void*)(g), \
    (__attribute__((address_space(3))) void*)(l), 16, 0, 0)

__device__ __forceinline__ float2 cmul(float2 a, float2 b) {
    return make_float2(a.x*b.x - a.y*b.y, a.x*b.y + a.y*b.x);
}
__device__ __forceinline__ void cfma(float2& acc, float2 a, float2 b) {
    acc.x = fmaf(a.x, b.x, acc.x); acc.x = fmaf(-a.y, b.y, acc.x);
    acc.y = fmaf(a.x, b.y, acc.y); acc.y = fmaf( a.y, b.x, acc.y);
}

// ---- PREP: grid 9217.
// bids 0..8191: u fp32->bf16 (8 floats/thread)
// 8192..8703: B1G; 8704..9215: B3G; 9216: lambda scalars
__global__ void prep(const float* __restrict__ u,
                     const float* __restrict__ Bmat, const float* __restrict__ Cmat,
                     const float* __restrict__ Lre, const float* __restrict__ Lim,
                     const float* __restrict__ logstep, float2* __restrict__ ws) {
    int bid = blockIdx.x;
    if (bid < 8192) {
        long i = ((long)bid * 256 + threadIdx.x) * 8;
        float4 v0 = *(const float4*)(u + i);
        float4 v1 = *(const float4*)(u + i + 4);
        __align__(16) __hip_bfloat162 t[4];
        t[0] = __float22bfloat162_rn(make_float2(v0.x, v0.y));
        t[1] = __float22bfloat162_rn(make_float2(v0.z, v0.w));
        t[2] = __float22bfloat162_rn(make_float2(v1.x, v1.y));
        t[3] = __float22bfloat162_rn(make_float2(v1.z, v1.w));
        *(bf16x8*)((__hip_bfloat16*)(ws + UB16_OFF) + i) = *(const bf16x8*)t;
    } else if (bid < 8704) {
        int idx = (bid - 8192) * 256 + threadIdx.x;  // = p*512+h
        int p = idx >> 9, h = idx & 511;
        double lr = (double)Lre[p], li = (double)Lim[p];
        double st = exp((double)logstep[p]);
        double a  = lr * st, th = li * st;
        double er = exp(a);
        double lamr = er * cos(th), lami = er * sin(th);
        double nr = lamr - 1.0, ni = lami;
        double den = lr*lr + li*li;
        float gx = (float)((nr*lr + ni*li)/den), gy = (float)((ni*lr - nr*li)/den);
        float2 b = ((const float2*)Bmat)[idx];
        float re = gx*b.x - gy*b.y;
        float im = gx*b.y + gy*b.x;
        __hip_bfloat16* B1 = (__hip_bfloat16*)(ws + B1G_OFF);
        B1[(2*p)*512 + h]   = __float2bfloat16(re);
        B1[(2*p+1)*512 + h] = __float2bfloat16(im);
    } else if (bid < 9216) {
        int idx = (bid - 8704) * 256 + threadIdx.x;  // = h*256+p
        int h = idx >> 8, p = idx & 255;
        float2 c = ((const float2*)Cmat)[idx];
        __hip_bfloat162* B3 = (__hip_bfloat162*)(ws + B3G_OFF);
        B3[h*256 + p] = __float22bfloat162_rn(make_float2(2.f*c.x, -2.f*c.y));
    } else {
        int p = threadIdx.x;
        double lr = (double)Lre[p], li = (double)Lim[p];
        double st = exp((double)logstep[p]);
        double a  = lr * st, th = li * st;
        double er = exp(a);
        ws[LAM_OFF + p] = make_float2((float)(er*cos(th)), (float)(er*sin(th)));
        double er64 = exp(64.0 * a), th64 = 64.0 * th;
        ((double2*)(ws + LAMS64D_OFF))[p] = make_double2(er64*cos(th64), er64*sin(th64));
    }
}

// ---- MFMA GEMM (R4-proven structure + XCD swizzle): 128x128 tile, BK=32 ----
// EPI=0: Cout bf16 = acc. EPI=1: Cout fp32 = acc + Dv[col]*u_bf16.
template<int EPI>
__global__ void gemm_mfma(const __hip_bfloat16* __restrict__ Ab,
                          const __hip_bfloat16* __restrict__ Bg,
                          void* __restrict__ Cout,
                          const __hip_bfloat16* __restrict__ ub,
                          const float* __restrict__ Dv) {
    __shared__ __align__(16) char lds[16384];   // A [0,8K), B [8K,16K)
    const int tid = threadIdx.x;
    const int idx = blockIdx.x;
    const int mt  = (idx >> 5) * 8 + (idx & 7);   // XCD swizzle
    const int nt  = (idx >> 3) & 3;
    const long r0 = (long)mt * 128;
    const int  n0 = nt * 128;

    const int rowL = tid >> 2;
    const int seg  = tid & 3;
    const __hip_bfloat16* Asrc = Ab + (r0 + rowL) * 512 + seg * 8;
    const __hip_bfloat16* Bsrc = Bg + (long)(n0 + rowL) * 512 + seg * 8;
    char* ldsA = lds + tid * 16;
    char* ldsB = lds + 8192 + tid * 16;

    const int lane = tid & 63;
    const int quad = lane >> 4;
    const int ml   = lane & 15;
    const int w    = tid >> 6;
    const int wm   = w & 1, wn = w >> 1;

    floatx4 acc[4][4];
    #pragma unroll
    for (int i = 0; i < 4; ++i)
        #pragma unroll
        for (int j = 0; j < 4; ++j) acc[i][j] = (floatx4)0.f;

    for (int kt = 0; kt < 16; ++kt) {
        __syncthreads();
        GLL16(Asrc + kt*32,           ldsA);
        GLL16(Asrc + kt*32 + 64*512,  ldsA + 4096);
        GLL16(Bsrc + kt*32,           ldsB);
        GLL16(Bsrc + kt*32 + 64*512,  ldsB + 4096);
        __syncthreads();

        bf16x8 af[4], bfr[4];
        #pragma unroll
        for (int fm = 0; fm < 4; ++fm)
            af[fm] = *(const bf16x8*)(lds + (wm*64 + fm*16 + ml)*64 + quad*16);
        #pragma unroll
        for (int fn = 0; fn < 4; ++fn)
            bfr[fn] = *(const bf16x8*)(lds + 8192 + (wn*64 + fn*16 + ml)*64 + quad*16);
        #pragma unroll
        for (int fm = 0; fm < 4; ++fm)
            #pragma unroll
            for (int fn = 0; fn < 4; ++fn)
                acc[fm][fn] = __builtin_amdgcn_mfma_f32_16x16x32_bf16(af[fm], bfr[fn], acc[fm][fn], 0, 0, 0);
    }

    #pragma unroll
    for (int fm = 0; fm < 4; ++fm)
        #pragma unroll
        for (int fn = 0; fn < 4; ++fn) {
            int col = n0 + wn*64 + fn*16 + ml;
            float d = (EPI == 1) ? Dv[col] : 0.f;
            #pragma unroll
            for (int reg = 0; reg < 4; ++reg) {
                long row = r0 + wm*64 + fm*16 + quad*4 + reg;
                long o = row * 512 + col;
                if (EPI == 0) {
                    ((__hip_bfloat16*)Cout)[o] = __float2bfloat16(acc[fm][fn][reg]);
                } else {
                    ((float*)Cout)[o] = acc[fm][fn][reg] + d * __bfloat162float(ub[o]);
                }
            }
        }
}

// ---- K2a: chunk aggregates, lambda-power ILP grouping ----
__global__ void k2a(float2* __restrict__ ws) {
    int p = threadIdx.x;
    int bc = blockIdx.x;              // b*NC + c
    int b = bc >> 6, c = bc & 63;
    float2 lam = ws[LAM_OFF + p];
    float2 lp[8];
    lp[0] = make_float2(1.f, 0.f);
    #pragma unroll
    for (int k = 1; k < 8; ++k) lp[k] = cmul(lp[k-1], lam);
    float2 lam8 = cmul(lp[7], lam);
    const __hip_bfloat162* __restrict__ bub = (const __hip_bfloat162*)(ws + BUB_OFF);
    long base = (long)(b*Ll + c*Sc) * Pp + p;
    float2 agg = make_float2(0.f, 0.f);
    for (int j0 = 0; j0 < Sc; j0 += 8) {
        float2 v[8];
        #pragma unroll
        for (int i = 0; i < 8; ++i)
            v[i] = __bfloat1622float2(bub[base + (long)(j0 + i) * Pp]);
        float2 s0 = make_float2(0.f, 0.f), s1 = make_float2(0.f, 0.f);
        #pragma unroll
        for (int i = 0; i < 8; i += 2) {
            cfma(s0, lp[7 - i], v[i]);
            cfma(s1, lp[6 - i], v[i + 1]);
        }
        float2 G = make_float2(s0.x + s1.x, s0.y + s1.y);
        float2 na = cmul(lam8, agg);
        agg = make_float2(na.x + G.x, na.y + G.y);
    }
    ws[AGG_OFF + bc * Pp + p] = agg;
}

// ---- K2c: fp64 carry prefix + apply + write xs bf16 + state planar ----
__global__ void k2c(float2* __restrict__ ws, float* __restrict__ dout) {
    int p = threadIdx.x;
    int bc = blockIdx.x;
    int b = bc >> 6, c = bc & 63;
    float2 lam = ws[LAM_OFF + p];
    double2 l64 = ((const double2*)(ws + LAMS64D_OFF))[p];
    double cr = 0.0, ci = 0.0;
    for (int cp = 0; cp < c; ++cp) {
        float2 a = ws[AGG_OFF + (b*NC + cp) * Pp + p];
        double nr = fma(l64.x, cr, (double)a.x); nr = fma(-l64.y, ci, nr);
        double ni = fma(l64.x, ci, (double)a.y); ni = fma( l64.y, cr, ni);
        cr = nr; ci = ni;
    }
    float2 x = make_float2((float)cr, (float)ci);
    const __hip_bfloat162* __restrict__ bub = (const __hip_bfloat162*)(ws + BUB_OFF);
    __hip_bfloat162* __restrict__ xsb = (__hip_bfloat162*)(ws + XSB_OFF);
    long base = (long)(b*Ll + c*Sc) * Pp + p;
    for (int j0 = 0; j0 < Sc; j0 += 8) {
        float2 v[8];
        #pragma unroll
        for (int i = 0; i < 8; ++i)
            v[i] = __bfloat1622float2(bub[base + (long)(j0 + i) * Pp]);
        #pragma unroll
        for (int i = 0; i < 8; ++i) {
            float nr = fmaf(lam.x, x.x, v[i].x); nr = fmaf(-lam.y, x.y, nr);
            float ni = fmaf(lam.x, x.y, v[i].y); ni = fmaf( lam.y, x.x, ni);
            x.x = nr; x.y = ni;
            xsb[base + (long)(j0 + i) * Pp] = __float22bfloat162_rn(make_float2(x.x, x.y));
        }
    }
    if (c == NC - 1) {
        dout[OUT_ELEMS + b * Pp + p] = x.x;
        dout[OUT_ELEMS + Bb * Pp + b * Pp + p] = x.y;
    }
}

extern "C" void kernel_launch(void* const* d_in, const int* in_sizes, int n_in,
                              void* d_out, int out_size, void* d_ws, size_t ws_size,
                              hipStream_t stream) {
    const float* u       = (const float*)d_in[0];
    const float* Lre     = (const float*)d_in[1];
    const float* Lim     = (const float*)d_in[2];
    const float* Bmat    = (const float*)d_in[3];
    const float* Cmat    = (const float*)d_in[4];
    const float* Dv      = (const float*)d_in[5];
    const float* logstep = (const float*)d_in[6];
    float*  out = (float*)d_out;
    float2* ws  = (float2*)d_ws;

    prep<<<9217, 256, 0, stream>>>(u, Bmat, Cmat, Lre, Lim, logstep, ws);

    gemm_mfma<0><<<1024, 256, 0, stream>>>(
        (const __hip_bfloat16*)(ws + UB16_OFF),
        (const __hip_bfloat16*)(ws + B1G_OFF),
        (void*)(ws + BUB_OFF), nullptr, nullptr);

    k2a<<<Bb*NC, 256, 0, stream>>>(ws);
    k2c<<<Bb*NC, 256, 0, stream>>>(ws, out);

    gemm_mfma<1><<<1024, 256, 0, stream>>>(
        (const __hip_bfloat16*)(ws + XSB_OFF),
        (const __hip_bfloat16*)(ws + B3G_OFF),
        (void*)out,
        (const __hip_bfloat16*)(ws + UB16_OFF), Dv);
}